// Round 1
// baseline (382.550 us; speedup 1.0000x reference)
//
#include <hip/hip_runtime.h>
#include <stdint.h>

typedef __bf16 bf16x8 __attribute__((ext_vector_type(8)));
typedef float f32x4 __attribute__((ext_vector_type(4)));

__device__ __forceinline__ unsigned int f2bf(float f) {
  unsigned int u = __float_as_uint(f);
  return (u + 0x7fffu + ((u >> 16) & 1u)) >> 16;  // RNE
}
__device__ __forceinline__ unsigned int pack2(float a, float b) {
  return f2bf(a) | (f2bf(b) << 16);
}

// ---------------------------------------------------------------------------
// K1: per-row  buf = x*SU ; FWHT(4096) ; *(1/64) ; -> bf16
// one block (256 thr) per row, 16 KB LDS
// ---------------------------------------------------------------------------
__global__ void __launch_bounds__(256) k_fwht_in(const float* __restrict__ X,
                                                 const float* __restrict__ SU,
                                                 unsigned short* __restrict__ Xh) {
  __shared__ float buf[4096];
  const int t = threadIdx.x;
  const size_t row = blockIdx.x;
  const float4* xr = (const float4*)(X + row * 4096);
  const float4* su = (const float4*)SU;
#pragma unroll
  for (int i = 0; i < 4; ++i) {
    int c = t + i * 256;
    float4 v = xr[c], s = su[c];
    buf[c * 4 + 0] = v.x * s.x;
    buf[c * 4 + 1] = v.y * s.y;
    buf[c * 4 + 2] = v.z * s.z;
    buf[c * 4 + 3] = v.w * s.w;
  }
  __syncthreads();
  int lh = 0;
  for (int h = 1; h < 4096; h <<= 1, ++lh) {
#pragma unroll
    for (int pi = 0; pi < 8; ++pi) {
      int p = t + pi * 256;
      int i = ((p >> lh) << (lh + 1)) | (p & (h - 1));
      int j = i + h;
      float a = buf[i], b = buf[j];
      buf[i] = a + b;
      buf[j] = a - b;
    }
    __syncthreads();
  }
  uint4* outv = (uint4*)(Xh + row * 4096);
#pragma unroll
  for (int i = 0; i < 2; ++i) {
    int c = t + i * 256;  // chunk of 8 elements
    const float* b8 = &buf[c * 8];
    uint4 o;
    o.x = pack2(b8[0] * 0.015625f, b8[1] * 0.015625f);
    o.y = pack2(b8[2] * 0.015625f, b8[3] * 0.015625f);
    o.z = pack2(b8[4] * 0.015625f, b8[5] * 0.015625f);
    o.w = pack2(b8[6] * 0.015625f, b8[7] * 0.015625f);
    outv[c] = o;
  }
}

// ---------------------------------------------------------------------------
// K2: W[m][k] (bf16) = grid[Qidxs[m][k/8]][k%8] ; one thread per Qidxs entry
// ---------------------------------------------------------------------------
__global__ void __launch_bounds__(256) k_decompress(const int* __restrict__ Qidxs,
                                                    const float* __restrict__ G,
                                                    unsigned short* __restrict__ Wh) {
  int e = blockIdx.x * 256 + threadIdx.x;  // 0 .. 2M-1
  int idx = Qidxs[e];
  const float4* g = (const float4*)(G + (size_t)idx * 8);
  float4 a = g[0], b = g[1];
  uint4 o;
  o.x = pack2(a.x, a.y);
  o.y = pack2(a.z, a.w);
  o.z = pack2(b.x, b.y);
  o.w = pack2(b.z, b.w);
  ((uint4*)Wh)[e] = o;
}

// ---------------------------------------------------------------------------
// K3: C[4096][4096] fp32 = A[4096][4096] bf16 @ B^T, B stored [n][k] bf16
// m97 recipe: 128x128 tile, BK=64, 4 waves 2x2, 16x16x32 MFMA 4x4/wave,
// global_load_lds dwordx4 staging, two-barrier K loop.
// ---------------------------------------------------------------------------
__device__ __forceinline__ void gl2lds16(const unsigned short* g, unsigned short* l) {
  __builtin_amdgcn_global_load_lds(
      (const __attribute__((address_space(1))) void*)g,
      (__attribute__((address_space(3))) void*)l, 16, 0, 0);
}

__global__ void __launch_bounds__(256) k_gemm_bt(const unsigned short* __restrict__ A,
                                                 const unsigned short* __restrict__ B,
                                                 float* __restrict__ C) {
  const int K = 4096, N = 4096;
  __shared__ unsigned short sA[128 * 64];
  __shared__ unsigned short sB[128 * 64];
  const int tid = threadIdx.x;
  const int wave = tid >> 6, lane = tid & 63;
  const int bn = blockIdx.x, bm = blockIdx.y;
  const int wr = wave >> 1, wc = wave & 1;
  const int frow = lane & 15, fk = (lane >> 4) * 8;
  f32x4 acc[4][4] = {};

  const size_t rowA0 = (size_t)bm * 128;
  const size_t rowB0 = (size_t)bn * 128;

  for (int kt = 0; kt < K; kt += 64) {
    __syncthreads();  // previous tile's ds_reads done before overwrite
#pragma unroll
    for (int it = 0; it < 4; ++it) {
      int c = it * 256 + tid;
      int r = c >> 3;
      int kc = (c & 7) * 8;
      // wave-uniform LDS base; HW adds lane*16
      unsigned short* la = &sA[(it * 256 + wave * 64) * 8];
      unsigned short* lb = &sB[(it * 256 + wave * 64) * 8];
      gl2lds16(A + (rowA0 + r) * K + kt + kc, la);
      gl2lds16(B + (rowB0 + r) * K + kt + kc, lb);
    }
    __syncthreads();  // drains vmcnt: staged tile visible
#pragma unroll
    for (int kk = 0; kk < 64; kk += 32) {
      bf16x8 af[4], bfr[4];
#pragma unroll
      for (int i = 0; i < 4; ++i)
        af[i] = *(const bf16x8*)&sA[(wr * 64 + i * 16 + frow) * 64 + kk + fk];
#pragma unroll
      for (int j = 0; j < 4; ++j)
        bfr[j] = *(const bf16x8*)&sB[(wc * 64 + j * 16 + frow) * 64 + kk + fk];
#pragma unroll
      for (int i = 0; i < 4; ++i)
#pragma unroll
        for (int j = 0; j < 4; ++j)
          acc[i][j] = __builtin_amdgcn_mfma_f32_16x16x32_bf16(af[i], bfr[j], acc[i][j], 0, 0, 0);
    }
  }
  // C/D layout: col = lane&15, row = (lane>>4)*4 + reg   [m89/m91 verified]
  const int crow = bm * 128 + wr * 64 + (lane >> 4) * 4;
  const int ccol = bn * 128 + wc * 64 + (lane & 15);
#pragma unroll
  for (int i = 0; i < 4; ++i)
#pragma unroll
    for (int j = 0; j < 4; ++j) {
      float* cp = C + (size_t)(crow + i * 16) * N + ccol + j * 16;
#pragma unroll
      for (int r = 0; r < 4; ++r) cp[(size_t)r * N] = acc[i][j][r];
    }
}

// ---------------------------------------------------------------------------
// K4: in-place per-row FWHT(4096) on fp32 output ; * SV * (1/64)
// ---------------------------------------------------------------------------
__global__ void __launch_bounds__(256) k_fwht_out(float* __restrict__ Y,
                                                  const float* __restrict__ SV) {
  __shared__ float buf[4096];
  const int t = threadIdx.x;
  const size_t row = blockIdx.x;
  float4* yr = (float4*)(Y + row * 4096);
#pragma unroll
  for (int i = 0; i < 4; ++i) {
    int c = t + i * 256;
    float4 v = yr[c];
    buf[c * 4 + 0] = v.x;
    buf[c * 4 + 1] = v.y;
    buf[c * 4 + 2] = v.z;
    buf[c * 4 + 3] = v.w;
  }
  __syncthreads();
  int lh = 0;
  for (int h = 1; h < 4096; h <<= 1, ++lh) {
#pragma unroll
    for (int pi = 0; pi < 8; ++pi) {
      int p = t + pi * 256;
      int i = ((p >> lh) << (lh + 1)) | (p & (h - 1));
      int j = i + h;
      float a = buf[i], b = buf[j];
      buf[i] = a + b;
      buf[j] = a - b;
    }
    __syncthreads();
  }
  const float4* sv = (const float4*)SV;
#pragma unroll
  for (int i = 0; i < 4; ++i) {
    int c = t + i * 256;
    float4 s = sv[c];
    float4 o;
    o.x = buf[c * 4 + 0] * s.x * 0.015625f;
    o.y = buf[c * 4 + 1] * s.y * 0.015625f;
    o.z = buf[c * 4 + 2] * s.z * 0.015625f;
    o.w = buf[c * 4 + 3] * s.w * 0.015625f;
    yr[c] = o;
  }
}

// ---------------------------------------------------------------------------
extern "C" void kernel_launch(void* const* d_in, const int* in_sizes, int n_in,
                              void* d_out, int out_size, void* d_ws, size_t ws_size,
                              hipStream_t stream) {
  const float* X     = (const float*)d_in[0];  // (2,2048,4096) fp32
  const float* SU    = (const float*)d_in[1];  // (4096,)
  const float* SV    = (const float*)d_in[2];  // (4096,)
  const float* G     = (const float*)d_in[3];  // (65536,8)
  const int*   Qidxs = (const int*)d_in[4];    // (4096,512)
  float* out = (float*)d_out;                  // (2,2048,4096) fp32

  unsigned short* Xh = (unsigned short*)d_ws;            // 4096*4096 bf16 = 32 MB
  unsigned short* Wh = Xh + (size_t)4096 * 4096;         // 4096*4096 bf16 = 32 MB

  k_fwht_in<<<4096, 256, 0, stream>>>(X, SU, Xh);
  k_decompress<<<(4096 * 512) / 256, 256, 0, stream>>>(Qidxs, G, Wh);
  k_gemm_bt<<<dim3(32, 32), 256, 0, stream>>>(Xh, Wh, out);
  k_fwht_out<<<4096, 256, 0, stream>>>(out, SV);
}

// Round 2
// 347.747 us; speedup vs baseline: 1.1001x; 1.1001x over previous
//
#include <hip/hip_runtime.h>
#include <stdint.h>

typedef __bf16 bf16x8 __attribute__((ext_vector_type(8)));
typedef float f32x4 __attribute__((ext_vector_type(4)));

__device__ __forceinline__ unsigned int f2bf(float f) {
  unsigned int u = __float_as_uint(f);
  return (u + 0x7fffu + ((u >> 16) & 1u)) >> 16;  // RNE
}
__device__ __forceinline__ unsigned int pack2(float a, float b) {
  return f2bf(a) | (f2bf(b) << 16);
}

// ---------------------------------------------------------------------------
// K1: per-row  buf = x*SU ; FWHT(4096) ; *(1/64) ; -> bf16
// ---------------------------------------------------------------------------
__global__ void __launch_bounds__(256) k_fwht_in(const float* __restrict__ X,
                                                 const float* __restrict__ SU,
                                                 unsigned short* __restrict__ Xh) {
  __shared__ float buf[4096];
  const int t = threadIdx.x;
  const size_t row = blockIdx.x;
  const float4* xr = (const float4*)(X + row * 4096);
  const float4* su = (const float4*)SU;
#pragma unroll
  for (int i = 0; i < 4; ++i) {
    int c = t + i * 256;
    float4 v = xr[c], s = su[c];
    buf[c * 4 + 0] = v.x * s.x;
    buf[c * 4 + 1] = v.y * s.y;
    buf[c * 4 + 2] = v.z * s.z;
    buf[c * 4 + 3] = v.w * s.w;
  }
  __syncthreads();
  int lh = 0;
  for (int h = 1; h < 4096; h <<= 1, ++lh) {
#pragma unroll
    for (int pi = 0; pi < 8; ++pi) {
      int p = t + pi * 256;
      int i = ((p >> lh) << (lh + 1)) | (p & (h - 1));
      int j = i + h;
      float a = buf[i], b = buf[j];
      buf[i] = a + b;
      buf[j] = a - b;
    }
    __syncthreads();
  }
  uint4* outv = (uint4*)(Xh + row * 4096);
#pragma unroll
  for (int i = 0; i < 2; ++i) {
    int c = t + i * 256;
    const float* b8 = &buf[c * 8];
    uint4 o;
    o.x = pack2(b8[0] * 0.015625f, b8[1] * 0.015625f);
    o.y = pack2(b8[2] * 0.015625f, b8[3] * 0.015625f);
    o.z = pack2(b8[4] * 0.015625f, b8[5] * 0.015625f);
    o.w = pack2(b8[6] * 0.015625f, b8[7] * 0.015625f);
    outv[c] = o;
  }
}

// ---------------------------------------------------------------------------
// K2: W[m][k] (bf16) = grid[Qidxs[m][k/8]][k%8]
// ---------------------------------------------------------------------------
__global__ void __launch_bounds__(256) k_decompress(const int* __restrict__ Qidxs,
                                                    const float* __restrict__ G,
                                                    unsigned short* __restrict__ Wh) {
  int e = blockIdx.x * 256 + threadIdx.x;
  int idx = Qidxs[e];
  const float4* g = (const float4*)(G + (size_t)idx * 8);
  float4 a = g[0], b = g[1];
  uint4 o;
  o.x = pack2(a.x, a.y);
  o.y = pack2(a.z, a.w);
  o.z = pack2(b.x, b.y);
  o.w = pack2(b.z, b.w);
  ((uint4*)Wh)[e] = o;
}

// ---------------------------------------------------------------------------
// K3: GEMM C = A @ B^T (both bf16 [4096][4096], K-major rows), fp32 out.
// m97 recipe + XOR bank-conflict swizzle applied on the GLOBAL address:
//   LDS slot (r, j) holds global chunk (r, j ^ (r&7))  [chunk = 8 bf16 = 16B]
// Readers fetch slot (row, jn ^ (row&7)). 16-way conflict -> 2-way (free).
// ---------------------------------------------------------------------------
__device__ __forceinline__ void gl2lds16(const unsigned short* g, unsigned short* l) {
  __builtin_amdgcn_global_load_lds(
      (const __attribute__((address_space(1))) void*)g,
      (__attribute__((address_space(3))) void*)l, 16, 0, 0);
}

__global__ void __launch_bounds__(256) k_gemm_bt(const unsigned short* __restrict__ A,
                                                 const unsigned short* __restrict__ B,
                                                 float* __restrict__ C) {
  const int K = 4096, N = 4096;
  __shared__ unsigned short sA[128 * 64];
  __shared__ unsigned short sB[128 * 64];
  const int tid = threadIdx.x;
  const int wave = tid >> 6, lane = tid & 63;
  const int bn = blockIdx.x, bm = blockIdx.y;
  const int wr = wave >> 1, wc = wave & 1;
  const int frow = lane & 15;
  const int sw = frow & 7;          // reader-side swizzle (row&7; wr*64,i*16 are mult of 8)
  const int jbase = lane >> 4;      // nominal chunk from lane's k-slice
  f32x4 acc[4][4] = {};

  const size_t rowA0 = (size_t)bm * 128;
  const size_t rowB0 = (size_t)bn * 128;

  // staging: this thread fills LDS chunk c = it*256+tid  ->  (r = c>>3, j = c&7)
  // from global chunk (r, j ^ (r&7))
  for (int kt = 0; kt < K; kt += 64) {
    __syncthreads();
#pragma unroll
    for (int it = 0; it < 4; ++it) {
      int c = it * 256 + tid;
      int r = c >> 3;
      int jg = (c & 7) ^ (r & 7);   // swizzled global chunk index
      int kc = jg * 8;
      unsigned short* la = &sA[(it * 256 + wave * 64) * 8];
      unsigned short* lb = &sB[(it * 256 + wave * 64) * 8];
      gl2lds16(A + (rowA0 + r) * K + kt + kc, la);
      gl2lds16(B + (rowB0 + r) * K + kt + kc, lb);
    }
    __syncthreads();
#pragma unroll
    for (int kk = 0; kk < 64; kk += 32) {
      bf16x8 af[4], bfr[4];
      int jn = (kk >> 3) + jbase;   // nominal chunk index
      int js = jn ^ sw;             // swizzled LDS chunk
#pragma unroll
      for (int i = 0; i < 4; ++i)
        af[i] = *(const bf16x8*)&sA[(wr * 64 + i * 16 + frow) * 64 + js * 8];
#pragma unroll
      for (int j = 0; j < 4; ++j)
        bfr[j] = *(const bf16x8*)&sB[(wc * 64 + j * 16 + frow) * 64 + js * 8];
#pragma unroll
      for (int i = 0; i < 4; ++i)
#pragma unroll
        for (int j = 0; j < 4; ++j)
          acc[i][j] = __builtin_amdgcn_mfma_f32_16x16x32_bf16(af[i], bfr[j], acc[i][j], 0, 0, 0);
    }
  }
  const int crow = bm * 128 + wr * 64 + (lane >> 4) * 4;
  const int ccol = bn * 128 + wc * 64 + (lane & 15);
#pragma unroll
  for (int i = 0; i < 4; ++i)
#pragma unroll
    for (int j = 0; j < 4; ++j) {
      float* cp = C + (size_t)(crow + i * 16) * N + ccol + j * 16;
#pragma unroll
      for (int r = 0; r < 4; ++r) cp[(size_t)r * N] = acc[i][j][r];
    }
}

// ---------------------------------------------------------------------------
// K4: in-place per-row FWHT(4096) on fp32 output ; * SV * (1/64)
// ---------------------------------------------------------------------------
__global__ void __launch_bounds__(256) k_fwht_out(float* __restrict__ Y,
                                                  const float* __restrict__ SV) {
  __shared__ float buf[4096];
  const int t = threadIdx.x;
  const size_t row = blockIdx.x;
  float4* yr = (float4*)(Y + row * 4096);
#pragma unroll
  for (int i = 0; i < 4; ++i) {
    int c = t + i * 256;
    float4 v = yr[c];
    buf[c * 4 + 0] = v.x;
    buf[c * 4 + 1] = v.y;
    buf[c * 4 + 2] = v.z;
    buf[c * 4 + 3] = v.w;
  }
  __syncthreads();
  int lh = 0;
  for (int h = 1; h < 4096; h <<= 1, ++lh) {
#pragma unroll
    for (int pi = 0; pi < 8; ++pi) {
      int p = t + pi * 256;
      int i = ((p >> lh) << (lh + 1)) | (p & (h - 1));
      int j = i + h;
      float a = buf[i], b = buf[j];
      buf[i] = a + b;
      buf[j] = a - b;
    }
    __syncthreads();
  }
  const float4* sv = (const float4*)SV;
#pragma unroll
  for (int i = 0; i < 4; ++i) {
    int c = t + i * 256;
    float4 s = sv[c];
    float4 o;
    o.x = buf[c * 4 + 0] * s.x * 0.015625f;
    o.y = buf[c * 4 + 1] * s.y * 0.015625f;
    o.z = buf[c * 4 + 2] * s.z * 0.015625f;
    o.w = buf[c * 4 + 3] * s.w * 0.015625f;
    yr[c] = o;
  }
}

// ---------------------------------------------------------------------------
extern "C" void kernel_launch(void* const* d_in, const int* in_sizes, int n_in,
                              void* d_out, int out_size, void* d_ws, size_t ws_size,
                              hipStream_t stream) {
  const float* X     = (const float*)d_in[0];
  const float* SU    = (const float*)d_in[1];
  const float* SV    = (const float*)d_in[2];
  const float* G     = (const float*)d_in[3];
  const int*   Qidxs = (const int*)d_in[4];
  float* out = (float*)d_out;

  unsigned short* Xh = (unsigned short*)d_ws;
  unsigned short* Wh = Xh + (size_t)4096 * 4096;

  k_fwht_in<<<4096, 256, 0, stream>>>(X, SU, Xh);
  k_decompress<<<(4096 * 512) / 256, 256, 0, stream>>>(Qidxs, G, Wh);
  k_gemm_bt<<<dim3(32, 32), 256, 0, stream>>>(Xh, Wh, out);
  k_fwht_out<<<4096, 256, 0, stream>>>(out, SV);
}

// Round 3
// 317.669 us; speedup vs baseline: 1.2042x; 1.0947x over previous
//
#include <hip/hip_runtime.h>
#include <stdint.h>

typedef __bf16 bf16x8 __attribute__((ext_vector_type(8)));
typedef float f32x4 __attribute__((ext_vector_type(4)));

__device__ __forceinline__ unsigned int f2bf(float f) {
  unsigned int u = __float_as_uint(f);
  return (u + 0x7fffu + ((u >> 16) & 1u)) >> 16;  // RNE
}
__device__ __forceinline__ unsigned int pack2(float a, float b) {
  return f2bf(a) | (f2bf(b) << 16);
}

// In-register 16-point FWHT (4 stages, fully unrolled)
__device__ __forceinline__ void fwht16(float v[16]) {
#pragma unroll
  for (int s = 0; s < 4; ++s) {
    const int h = 1 << s;
#pragma unroll
    for (int i = 0; i < 16; ++i) {
      if (!(i & h)) {
        float a = v[i], b = v[i ^ h];
        v[i] = a + b;
        v[i ^ h] = a - b;
      }
    }
  }
}

#define LP(i) ((i) + ((i) >> 5))  // padded LDS index: +1 float per 32

// ---------------------------------------------------------------------------
// K1: per-row  FWHT(4096)(x*SU) * (1/64) -> bf16
// radix-16 register FWHT: 3 phases (bits 0-3, 4-7, 8-11), 2 LDS exchanges.
// ---------------------------------------------------------------------------
__global__ void __launch_bounds__(256) k_fwht_in(const float* __restrict__ X,
                                                 const float* __restrict__ SU,
                                                 unsigned short* __restrict__ Xh) {
  __shared__ float lds[4224];  // 4096 + 128 pad
  const int t = threadIdx.x;
  const size_t row = blockIdx.x;
  const float4* xr = (const float4*)(X + row * 4096);
  const float4* su = (const float4*)SU;
  float v[16];
  // load contiguous elements 16t..16t+15, fold SU
#pragma unroll
  for (int q = 0; q < 4; ++q) {
    float4 a = xr[4 * t + q], s = su[4 * t + q];
    v[4 * q + 0] = a.x * s.x;
    v[4 * q + 1] = a.y * s.y;
    v[4 * q + 2] = a.z * s.z;
    v[4 * q + 3] = a.w * s.w;
  }
  fwht16(v);  // bits 0-3
#pragma unroll
  for (int q = 0; q < 4; ++q) {
    int i0 = 16 * t + 4 * q;  // float4 stays within a 32-block: LP contiguous
    *(float4*)&lds[LP(i0)] = make_float4(v[4 * q], v[4 * q + 1], v[4 * q + 2], v[4 * q + 3]);
  }
  __syncthreads();
  // phase B: bits 4-7; thread owns base b = (t>>4)<<8 | (t&15), indices b+16j
  const int b = ((t >> 4) << 8) | (t & 15);
#pragma unroll
  for (int j = 0; j < 16; ++j) { int i = b + 16 * j; v[j] = lds[LP(i)]; }
  fwht16(v);
#pragma unroll
  for (int j = 0; j < 16; ++j) { int i = b + 16 * j; lds[LP(i)] = v[j]; }
  __syncthreads();
  // phase C: bits 8-11; thread owns indices t + 256j
#pragma unroll
  for (int j = 0; j < 16; ++j) { int i = t + 256 * j; v[j] = lds[LP(i)]; }
  fwht16(v);
  unsigned short* orow = Xh + row * 4096;
#pragma unroll
  for (int j = 0; j < 16; ++j)
    orow[t + 256 * j] = (unsigned short)f2bf(v[j] * 0.015625f);
}

// ---------------------------------------------------------------------------
// K2: W[m][k] (bf16) = grid[Qidxs[m][k/8]][k%8]
// ---------------------------------------------------------------------------
__global__ void __launch_bounds__(256) k_decompress(const int* __restrict__ Qidxs,
                                                    const float* __restrict__ G,
                                                    unsigned short* __restrict__ Wh) {
  int e = blockIdx.x * 256 + threadIdx.x;
  int idx = Qidxs[e];
  const float4* g = (const float4*)(G + (size_t)idx * 8);
  float4 a = g[0], b = g[1];
  uint4 o;
  o.x = pack2(a.x, a.y);
  o.y = pack2(a.z, a.w);
  o.z = pack2(b.x, b.y);
  o.w = pack2(b.z, b.w);
  ((uint4*)Wh)[e] = o;
}

// ---------------------------------------------------------------------------
// K3: GEMM C = A @ B^T (both bf16 [4096][4096], K-major rows), fp32 out.
// m97 recipe + XOR bank-conflict swizzle on the GLOBAL address (R2: conflicts
// 5.0e7 -> 0). LDS slot (r,j) holds global chunk (r, j^(r&7)); readers fetch
// slot (row, jn ^ (row&7)).
// ---------------------------------------------------------------------------
__device__ __forceinline__ void gl2lds16(const unsigned short* g, unsigned short* l) {
  __builtin_amdgcn_global_load_lds(
      (const __attribute__((address_space(1))) void*)g,
      (__attribute__((address_space(3))) void*)l, 16, 0, 0);
}

__global__ void __launch_bounds__(256) k_gemm_bt(const unsigned short* __restrict__ A,
                                                 const unsigned short* __restrict__ B,
                                                 float* __restrict__ C) {
  const int K = 4096, N = 4096;
  __shared__ unsigned short sA[128 * 64];
  __shared__ unsigned short sB[128 * 64];
  const int tid = threadIdx.x;
  const int wave = tid >> 6, lane = tid & 63;
  const int bn = blockIdx.x, bm = blockIdx.y;
  const int wr = wave >> 1, wc = wave & 1;
  const int frow = lane & 15;
  const int sw = frow & 7;
  const int jbase = lane >> 4;
  f32x4 acc[4][4] = {};

  const size_t rowA0 = (size_t)bm * 128;
  const size_t rowB0 = (size_t)bn * 128;

  for (int kt = 0; kt < K; kt += 64) {
    __syncthreads();
#pragma unroll
    for (int it = 0; it < 4; ++it) {
      int c = it * 256 + tid;
      int r = c >> 3;
      int jg = (c & 7) ^ (r & 7);
      int kc = jg * 8;
      unsigned short* la = &sA[(it * 256 + wave * 64) * 8];
      unsigned short* lb = &sB[(it * 256 + wave * 64) * 8];
      gl2lds16(A + (rowA0 + r) * K + kt + kc, la);
      gl2lds16(B + (rowB0 + r) * K + kt + kc, lb);
    }
    __syncthreads();
#pragma unroll
    for (int kk = 0; kk < 64; kk += 32) {
      bf16x8 af[4], bfr[4];
      int jn = (kk >> 3) + jbase;
      int js = jn ^ sw;
#pragma unroll
      for (int i = 0; i < 4; ++i)
        af[i] = *(const bf16x8*)&sA[(wr * 64 + i * 16 + frow) * 64 + js * 8];
#pragma unroll
      for (int j = 0; j < 4; ++j)
        bfr[j] = *(const bf16x8*)&sB[(wc * 64 + j * 16 + frow) * 64 + js * 8];
#pragma unroll
      for (int i = 0; i < 4; ++i)
#pragma unroll
        for (int j = 0; j < 4; ++j)
          acc[i][j] = __builtin_amdgcn_mfma_f32_16x16x32_bf16(af[i], bfr[j], acc[i][j], 0, 0, 0);
    }
  }
  const int crow = bm * 128 + wr * 64 + (lane >> 4) * 4;
  const int ccol = bn * 128 + wc * 64 + (lane & 15);
#pragma unroll
  for (int i = 0; i < 4; ++i)
#pragma unroll
    for (int j = 0; j < 4; ++j) {
      float* cp = C + (size_t)(crow + i * 16) * N + ccol + j * 16;
#pragma unroll
      for (int r = 0; r < 4; ++r) cp[(size_t)r * N] = acc[i][j][r];
    }
}

// ---------------------------------------------------------------------------
// K4: per-row FWHT(4096) on fp32 output ; * SV * (1/64) — radix-16 register
// ---------------------------------------------------------------------------
__global__ void __launch_bounds__(256) k_fwht_out(float* __restrict__ Y,
                                                  const float* __restrict__ SV) {
  __shared__ float lds[4224];
  const int t = threadIdx.x;
  const size_t row = blockIdx.x;
  float* yrow = Y + row * 4096;
  const float4* yr = (const float4*)yrow;
  float v[16];
#pragma unroll
  for (int q = 0; q < 4; ++q) {
    float4 a = yr[4 * t + q];
    v[4 * q + 0] = a.x;
    v[4 * q + 1] = a.y;
    v[4 * q + 2] = a.z;
    v[4 * q + 3] = a.w;
  }
  fwht16(v);  // bits 0-3
#pragma unroll
  for (int q = 0; q < 4; ++q) {
    int i0 = 16 * t + 4 * q;
    *(float4*)&lds[LP(i0)] = make_float4(v[4 * q], v[4 * q + 1], v[4 * q + 2], v[4 * q + 3]);
  }
  __syncthreads();
  const int b = ((t >> 4) << 8) | (t & 15);
#pragma unroll
  for (int j = 0; j < 16; ++j) { int i = b + 16 * j; v[j] = lds[LP(i)]; }
  fwht16(v);  // bits 4-7
#pragma unroll
  for (int j = 0; j < 16; ++j) { int i = b + 16 * j; lds[LP(i)] = v[j]; }
  __syncthreads();
#pragma unroll
  for (int j = 0; j < 16; ++j) { int i = t + 256 * j; v[j] = lds[LP(i)]; }
  fwht16(v);  // bits 8-11
#pragma unroll
  for (int j = 0; j < 16; ++j) {
    int i = t + 256 * j;
    yrow[i] = v[j] * SV[i] * 0.015625f;
  }
}

// ---------------------------------------------------------------------------
extern "C" void kernel_launch(void* const* d_in, const int* in_sizes, int n_in,
                              void* d_out, int out_size, void* d_ws, size_t ws_size,
                              hipStream_t stream) {
  const float* X     = (const float*)d_in[0];
  const float* SU    = (const float*)d_in[1];
  const float* SV    = (const float*)d_in[2];
  const float* G     = (const float*)d_in[3];
  const int*   Qidxs = (const int*)d_in[4];
  float* out = (float*)d_out;

  unsigned short* Xh = (unsigned short*)d_ws;
  unsigned short* Wh = Xh + (size_t)4096 * 4096;

  k_fwht_in<<<4096, 256, 0, stream>>>(X, SU, Xh);
  k_decompress<<<(4096 * 512) / 256, 256, 0, stream>>>(Qidxs, G, Wh);
  k_gemm_bt<<<dim3(32, 32), 256, 0, stream>>>(Xh, Wh, out);
  k_fwht_out<<<4096, 256, 0, stream>>>(out, SV);
}